// Round 12
// baseline (458.546 us; speedup 1.0000x reference)
//
#include <hip/hip_runtime.h>
#include <math.h>

#define IN_DIM 128
#define H1 64
#define H2 32
#define NC 8
#define SCAN_CH 1024   // elements per scan block (256 threads x 4)
#define NB_MAX 512     // max buckets (n <= 131072)
#define BLK 512        // edge partition blocks

typedef unsigned int u32;

__device__ __forceinline__ float bf_lo(u32 u) { return __uint_as_float(u << 16); }
__device__ __forceinline__ float bf_hi(u32 u) { return __uint_as_float(u & 0xffff0000u); }
__device__ __forceinline__ unsigned short f2b(float f) {  // RNE float->bf16
  u32 u = __float_as_uint(f);
  u += 0x7fffu + ((u >> 16) & 1u);
  return (unsigned short)(u >> 16);
}

// ---------------- P1: per-block bucket histogram (LDS atomics only) ----------------
// bucket(d) = d >> 8 (256 nodes per bucket).

__global__ __launch_bounds__(256) void k_hist(const int* __restrict__ dst,
                                              int* __restrict__ bh,
                                              int E, int EPB, int NBk) {
  __shared__ int h[NB_MAX];
  int k = blockIdx.x, tid = threadIdx.x;
  for (int i = tid; i < NBk; i += 256) h[i] = 0;
  __syncthreads();
  int st = k * EPB, en = min(E, st + EPB);
  for (int i = st + tid; i < en; i += 256)
    atomicAdd(&h[((u32)dst[i]) >> 8], 1);
  __syncthreads();
  for (int b = tid; b < NBk; b += 256) bh[b * BLK + k] = h[b];
}

// ---- generic 3-phase exclusive scan of A[L] -> S[L], S[L] = total ----

__global__ __launch_bounds__(256) void k_gsc1(const int* __restrict__ A,
                                              int* __restrict__ bsum, int L) {
  int b = blockIdx.x, tid = threadIdx.x;
  int i0 = b * SCAN_CH + tid * 4;
  int s = 0;
  if (i0 + 3 < L) {
    int4 v = *(const int4*)(A + i0);
    s = v.x + v.y + v.z + v.w;
  } else {
    for (int i = i0; i < L; ++i) s += A[i];
  }
  __shared__ int red[256];
  red[tid] = s;
  __syncthreads();
  for (int d = 128; d > 0; d >>= 1) {
    if (tid < d) red[tid] += red[tid + d];
    __syncthreads();
  }
  if (tid == 0) bsum[b] = red[0];
}

__global__ __launch_bounds__(256) void k_gsc2(const int* __restrict__ bsum,
                                              int* __restrict__ bbase,
                                              int* __restrict__ S, int nbk, int L) {
  __shared__ int part[256];
  int tid = threadIdx.x;
  int chunk = (nbk + 255) / 256;
  int st = tid * chunk, en = min(st + chunk, nbk);
  int s = 0;
  for (int i = st; i < en; ++i) s += bsum[i];
  part[tid] = s;
  __syncthreads();
  for (int d = 1; d < 256; d <<= 1) {
    int t = (tid >= d) ? part[tid - d] : 0;
    __syncthreads();
    part[tid] += t;
    __syncthreads();
  }
  int base = (tid == 0) ? 0 : part[tid - 1];
  for (int i = st; i < en; ++i) { bbase[i] = base; base += bsum[i]; }
  if (tid == 255) S[L] = part[255];
}

__global__ __launch_bounds__(256) void k_gsc3(const int* __restrict__ A,
                                              const int* __restrict__ bbase,
                                              int* __restrict__ S, int L) {
  int b = blockIdx.x, tid = threadIdx.x;
  int i0 = b * SCAN_CH + tid * 4;
  int e0 = 0, e1 = 0, e2 = 0, e3 = 0;
  if (i0 + 3 < L) {
    int4 v = *(const int4*)(A + i0);
    e0 = v.x; e1 = v.y; e2 = v.z; e3 = v.w;
  } else {
    if (i0 + 0 < L) e0 = A[i0 + 0];
    if (i0 + 1 < L) e1 = A[i0 + 1];
    if (i0 + 2 < L) e2 = A[i0 + 2];
    if (i0 + 3 < L) e3 = A[i0 + 3];
  }
  __shared__ int part[256];
  part[tid] = e0 + e1 + e2 + e3;
  __syncthreads();
  for (int d = 1; d < 256; d <<= 1) {
    int t = (tid >= d) ? part[tid - d] : 0;
    __syncthreads();
    part[tid] += t;
    __syncthreads();
  }
  int base = bbase[b] + ((tid == 0) ? 0 : part[tid - 1]);
  int o0 = base, o1 = o0 + e0, o2 = o1 + e1, o3 = o2 + e2;
  if (i0 + 3 < L) {
    int4 o; o.x = o0; o.y = o1; o.z = o2; o.w = o3;
    *(int4*)(S + i0) = o;
  } else {
    if (i0 + 0 < L) S[i0 + 0] = o0;
    if (i0 + 1 < L) S[i0 + 1] = o1;
    if (i0 + 2 < L) S[i0 + 2] = o2;
    if (i0 + 3 < L) S[i0 + 3] = o3;
  }
}

// ---------------- P3: bucket scatter (LDS cursors, disjoint global ranges) ----------------
// packed entry: bits[0,17) = src, bits[17,25) = local node id within bucket.

__global__ __launch_bounds__(256) void k_scatter(const int* __restrict__ src,
                                                 const int* __restrict__ dst,
                                                 const int* __restrict__ S,
                                                 u32* __restrict__ packed,
                                                 int E, int EPB, int NBk) {
  __shared__ int cur[NB_MAX];
  int k = blockIdx.x, tid = threadIdx.x;
  for (int b = tid; b < NBk; b += 256) cur[b] = S[b * BLK + k];
  __syncthreads();
  int st = k * EPB, en = min(E, st + EPB);
  for (int i = st + tid; i < en; i += 256) {
    int d = dst[i];
    int b = ((u32)d) >> 8;
    int pos = atomicAdd(&cur[b], 1);
    packed[pos] = (((u32)d & 255u) << 17) | (u32)src[i];
  }
}

// ---------------- P4: per-bucket CSR build + off + dinv (LDS only) ----------------

__global__ __launch_bounds__(256) void k_build(const u32* __restrict__ packed,
                                               const int* __restrict__ S,
                                               int* __restrict__ csr,
                                               int* __restrict__ off,
                                               float* __restrict__ dinv,
                                               int n, int NBk) {
  __shared__ int cnt[256];
  __shared__ int tmp[256];
  __shared__ int curh[256];
  int b = blockIdx.x, tid = threadIdx.x;
  int r0 = S[b * BLK];
  int r1 = S[(b + 1) * BLK];  // for last bucket: S[L] = E
  cnt[tid] = 0;
  __syncthreads();
  for (int i = r0 + tid; i < r1; i += 256)
    atomicAdd(&cnt[packed[i] >> 17], 1);
  __syncthreads();
  int v = cnt[tid];
  tmp[tid] = v;
  __syncthreads();
  for (int d = 1; d < 256; d <<= 1) {
    int t = (tid >= d) ? tmp[tid - d] : 0;
    __syncthreads();
    tmp[tid] += t;
    __syncthreads();
  }
  int base = r0 + tmp[tid] - v;  // exclusive position for this local node
  int node = b * 256 + tid;
  if (node < n) {
    off[node] = base;
    dinv[node] = rsqrtf((float)(v + 1));  // +1 self-loop
  }
  if (b == NBk - 1 && tid == 0) off[n] = r1;
  curh[tid] = base;
  __syncthreads();
  for (int i = r0 + tid; i < r1; i += 256) {
    u32 u = packed[i];
    int pos = atomicAdd(&curh[u >> 17], 1);
    csr[pos] = (int)(u & 0x1FFFFu);
  }
}

// ---------------- projection 1: h1p = bf16(dinv * (x @ W1^T))  [n,128]->[n,64] ----------------

__global__ void k_proj1(const float4* __restrict__ x4, const float* __restrict__ W1,
                        const float* __restrict__ dinv,
                        unsigned short* __restrict__ h1p, int n) {
  __shared__ float xs[16][IN_DIM];
  __shared__ float wt[IN_DIM][H1 + 1];
  int tid = threadIdx.x;
  int row0 = blockIdx.x * 16;

  for (int i = tid; i < (H1 * IN_DIM / 4); i += 256) {
    float4 w = ((const float4*)W1)[i];
    int o = (i * 4) / IN_DIM;
    int k = (i * 4) % IN_DIM;
    wt[k + 0][o] = w.x; wt[k + 1][o] = w.y; wt[k + 2][o] = w.z; wt[k + 3][o] = w.w;
  }
  for (int i = tid; i < 16 * IN_DIM / 4; i += 256) {
    int r = (i * 4) / IN_DIM, k = (i * 4) % IN_DIM;
    int row = row0 + r;
    if (row < n)
      *((float4*)&xs[r][k]) = x4[(size_t)row * (IN_DIM / 4) + k / 4];
  }
  __syncthreads();

  int o = tid & 63, rq = tid >> 6;
  float a0 = 0.f, a1 = 0.f, a2 = 0.f, a3 = 0.f;
  for (int k = 0; k < IN_DIM; ++k) {
    float w = wt[k][o];
    a0 += xs[rq * 4 + 0][k] * w;
    a1 += xs[rq * 4 + 1][k] * w;
    a2 += xs[rq * 4 + 2][k] * w;
    a3 += xs[rq * 4 + 3][k] * w;
  }
  int r = row0 + rq * 4;
  if (r + 0 < n) h1p[(size_t)(r + 0) * H1 + o] = f2b(a0 * dinv[r + 0]);
  if (r + 1 < n) h1p[(size_t)(r + 1) * H1 + o] = f2b(a1 * dinv[r + 1]);
  if (r + 2 < n) h1p[(size_t)(r + 2) * H1 + o] = f2b(a2 * dinv[r + 2]);
  if (r + 3 < n) h1p[(size_t)(r + 3) * H1 + o] = f2b(a3 * dinv[r + 3]);
}

// ---------------- fused: layer-1 gather-agg + bias + relu + proj2 ----------------
// Half-wave per edge slot, unroll x4 (8 edges in flight). csr/off loads are
// non-temporal: streaming data must not evict hp-table lines from L2.
// rows[wv] is wave-private LDS: per-wave DS ordering makes barriers unnecessary.

__global__ __launch_bounds__(256) void k_agg64_proj2(
    const u32* __restrict__ hp,    // [n][32] packed bf16x2
    const float* __restrict__ dinv,
    const int* __restrict__ off, const int* __restrict__ csr,
    const float* __restrict__ b1, const float* __restrict__ W2,
    unsigned short* __restrict__ h2p, int n) {
  __shared__ float wt[H1][H2 + 1];   // W2 transposed: wt[k][o]
  __shared__ float rows[4][H1];      // relu(out1) row per wave
  int tid = threadIdx.x;

  for (int i = tid; i < H2 * H1 / 4; i += 256) {
    float4 w = ((const float4*)W2)[i];
    int o = (i * 4) / H1, k = (i * 4) % H1;
    wt[k + 0][o] = w.x; wt[k + 1][o] = w.y; wt[k + 2][o] = w.z; wt[k + 3][o] = w.w;
  }

  int lane = tid & 63;
  int wv = __builtin_amdgcn_readfirstlane(tid >> 6);
  int wid0 = blockIdx.x * 4 + wv;
  int wid = wid0 < n ? wid0 : n - 1;   // clamp so all waves reach barriers
  int half = lane >> 5, f2 = lane & 31;

  float ax = 0.f, ay = 0.f;
  if (half == 0) {  // self term (table already has dinv[self] folded in)
    u32 u = hp[(size_t)wid * (H1 / 2) + f2];
    ax = bf_lo(u); ay = bf_hi(u);
  }
  int r0 = __builtin_nontemporal_load(off + wid);
  int r1 = __builtin_nontemporal_load(off + wid + 1);
  int i = r0 + half;
  for (; i + 6 < r1; i += 8) {
    int s0 = __builtin_nontemporal_load(csr + i + 0);
    int s1 = __builtin_nontemporal_load(csr + i + 2);
    int s2 = __builtin_nontemporal_load(csr + i + 4);
    int s3 = __builtin_nontemporal_load(csr + i + 6);
    u32 u0 = hp[(size_t)s0 * (H1 / 2) + f2];
    u32 u1 = hp[(size_t)s1 * (H1 / 2) + f2];
    u32 u2 = hp[(size_t)s2 * (H1 / 2) + f2];
    u32 u3 = hp[(size_t)s3 * (H1 / 2) + f2];
    ax += bf_lo(u0); ay += bf_hi(u0);
    ax += bf_lo(u1); ay += bf_hi(u1);
    ax += bf_lo(u2); ay += bf_hi(u2);
    ax += bf_lo(u3); ay += bf_hi(u3);
  }
  for (; i < r1; i += 2) {
    int s = __builtin_nontemporal_load(csr + i);
    u32 u = hp[(size_t)s * (H1 / 2) + f2];
    ax += bf_lo(u);
    ay += bf_hi(u);
  }
  ax += __shfl_down(ax, 32, 64);
  ay += __shfl_down(ay, 32, 64);
  float d = dinv[wid];
  // wt is needed below; one barrier covers its staging (placed after the
  // gather so waves that finish early don't re-stall).
  __syncthreads();
  if (half == 0) {
    float2 rv;
    rv.x = fmaxf(ax * d + b1[2 * f2 + 0], 0.f);
    rv.y = fmaxf(ay * d + b1[2 * f2 + 1], 0.f);
    *(float2*)&rows[wv][2 * f2] = rv;
  }
  // no block barrier: rows[wv] is written and read by the same wave (DS ops
  // from one wave execute in order).

  // proj2: half-wave split over k, 32 outputs per node
  int o = lane & 31;
  float a = 0.f;
#pragma unroll
  for (int k = 0; k < 32; ++k) {
    int kk = half * 32 + k;
    a += rows[wv][kk] * wt[kk][o];
  }
  a += __shfl_down(a, 32, 64);
  if (half == 0 && wid0 < n) h2p[(size_t)wid0 * H2 + o] = f2b(a * d);
}

// ---------------- fused: layer-2 gather-agg + b2 + gates + leaf ----------------
// Quarter-wave per edge slot, unroll x4 (16 edges in flight). nt csr loads;
// rowh/rowg are wave-private -> no block barriers in the epilogue.

__global__ __launch_bounds__(256) void k_agg32_tree(
    const u32* __restrict__ hp,    // [n][16] packed bf16x2
    const float* __restrict__ dinv,
    const int* __restrict__ off, const int* __restrict__ csr,
    const float* __restrict__ b2, const float* __restrict__ gate_w,
    const float* __restrict__ gate_b, const float* __restrict__ leaf_w,
    float* __restrict__ out, int n) {
  __shared__ float gwt[H2][H2 + 1];  // gate_w transposed: gwt[k][j]
  __shared__ float lws[H2][NC + 1];
  __shared__ float rowh[4][H2];
  __shared__ float rowg[4][H2];
  int tid = threadIdx.x;

  {
    float4 w = ((const float4*)gate_w)[tid];  // H2*H2/4 == 256
    int j = (tid * 4) / H2, k = (tid * 4) % H2;
    gwt[k + 0][j] = w.x; gwt[k + 1][j] = w.y; gwt[k + 2][j] = w.z; gwt[k + 3][j] = w.w;
  }
  lws[tid >> 3][tid & 7] = leaf_w[tid];  // H2*NC == 256

  int lane = tid & 63;
  int wv = __builtin_amdgcn_readfirstlane(tid >> 6);
  int wid0 = blockIdx.x * 4 + wv;
  int wid = wid0 < n ? wid0 : n - 1;
  int q = lane >> 4, f2 = lane & 15;

  float ax = 0.f, ay = 0.f;
  if (q == 0) {  // self term
    u32 u = hp[(size_t)wid * (H2 / 2) + f2];
    ax = bf_lo(u); ay = bf_hi(u);
  }
  int r0 = __builtin_nontemporal_load(off + wid);
  int r1 = __builtin_nontemporal_load(off + wid + 1);
  int i = r0 + q;
  for (; i + 12 < r1; i += 16) {
    int s0 = __builtin_nontemporal_load(csr + i + 0);
    int s1 = __builtin_nontemporal_load(csr + i + 4);
    int s2 = __builtin_nontemporal_load(csr + i + 8);
    int s3 = __builtin_nontemporal_load(csr + i + 12);
    u32 u0 = hp[(size_t)s0 * (H2 / 2) + f2];
    u32 u1 = hp[(size_t)s1 * (H2 / 2) + f2];
    u32 u2 = hp[(size_t)s2 * (H2 / 2) + f2];
    u32 u3 = hp[(size_t)s3 * (H2 / 2) + f2];
    ax += bf_lo(u0); ay += bf_hi(u0);
    ax += bf_lo(u1); ay += bf_hi(u1);
    ax += bf_lo(u2); ay += bf_hi(u2);
    ax += bf_lo(u3); ay += bf_hi(u3);
  }
  for (; i < r1; i += 4) {
    int s = __builtin_nontemporal_load(csr + i);
    u32 u = hp[(size_t)s * (H2 / 2) + f2];
    ax += bf_lo(u);
    ay += bf_hi(u);
  }
  ax += __shfl_down(ax, 32, 64); ay += __shfl_down(ay, 32, 64);
  ax += __shfl_down(ax, 16, 64); ay += __shfl_down(ay, 16, 64);
  float d = dinv[wid];
  __syncthreads();  // covers gwt/lws staging
  if (lane < 16) {
    float2 rv;
    rv.x = ax * d + b2[2 * f2 + 0];
    rv.y = ay * d + b2[2 * f2 + 1];
    *(float2*)&rowh[wv][2 * f2] = rv;
  }
  // no block barrier: rowh[wv] is wave-private

  // gates: j = f, half-wave split over k (16 each)
  int half = lane >> 5, f = lane & 31;
  float g = 0.f;
#pragma unroll
  for (int k = 0; k < 16; ++k) {
    int kk = half * 16 + k;
    g += rowh[wv][kk] * gwt[kk][f];
  }
  g += __shfl_down(g, 32, 64);
  if (half == 0) rowg[wv][f] = 1.0f / (1.0f + __expf(-(g + gate_b[f])));
  // no block barrier: rowg[wv] is wave-private

  // leaf: 8 groups of 8 lanes
  int c = lane & 7, gi = lane >> 3;
  float a = 0.f;
#pragma unroll
  for (int j4 = 0; j4 < 4; ++j4) {
    int jj = gi * 4 + j4;
    a += rowg[wv][jj] * lws[jj][c];
  }
  a += __shfl_down(a, 32, 64);
  a += __shfl_down(a, 16, 64);
  a += __shfl_down(a, 8, 64);
  if (lane < 8 && wid0 < n) out[(size_t)wid0 * NC + lane] = a;
}

// ---------------- host ----------------

extern "C" void kernel_launch(void* const* d_in, const int* in_sizes, int n_in,
                              void* d_out, int out_size, void* d_ws, size_t ws_size,
                              hipStream_t stream) {
  const float* x  = (const float*)d_in[0];
  const int*   ei = (const int*)d_in[1];
  const float* W1 = (const float*)d_in[2];
  const float* b1 = (const float*)d_in[3];
  const float* W2 = (const float*)d_in[4];
  const float* b2 = (const float*)d_in[5];
  const float* gw = (const float*)d_in[6];
  const float* gb = (const float*)d_in[7];
  const float* lw = (const float*)d_in[8];
  float* out = (float*)d_out;

  int n = in_sizes[0] / IN_DIM;
  int E = in_sizes[1] / 2;
  const int* src  = ei;
  const int* dstp = ei + E;

  int NBk = (n + 255) >> 8;                    // buckets of 256 nodes
  int EPB = (E + BLK - 1) / BLK;               // edges per partition block
  int L   = NBk * BLK;                         // blockhist entries
  int nbs = (L + SCAN_CH - 1) / SCAN_CH;       // scan blocks

  // workspace layout (16B-aligned chunks)
  size_t n4  = ((size_t)n + 3) & ~(size_t)3;
  size_t np4 = ((size_t)n + 1 + 3) & ~(size_t)3;
  size_t E4  = ((size_t)E + 3) & ~(size_t)3;
  size_t L4  = ((size_t)L + 1 + 3) & ~(size_t)3;
  size_t nbs4 = ((size_t)nbs + 3) & ~(size_t)3;
  char* w = (char*)d_ws;
  int* csr    = (int*)w;   w += E4 * 4;
  u32* packed = (u32*)w;   w += E4 * 4;
  int* bh     = (int*)w;   w += L4 * 4;
  int* S      = (int*)w;   w += L4 * 4;
  int* bsum   = (int*)w;   w += nbs4 * 4;
  int* bbase  = (int*)w;   w += nbs4 * 4;
  float* dinv = (float*)w; w += n4 * 4;
  int* off    = (int*)w;   w += np4 * 4;
  unsigned short* h1p = (unsigned short*)w;  w += n4 * (size_t)H1 * 2;  // bf16 [n][64]
  unsigned short* h2p = (unsigned short*)w;                             // bf16 [n][32]

  int gw4 = (n + 3) / 4;  // 4 nodes per 256-thread block

  k_hist<<<BLK, 256, 0, stream>>>(dstp, bh, E, EPB, NBk);
  k_gsc1<<<nbs, 256, 0, stream>>>(bh, bsum, L);
  k_gsc2<<<1, 256, 0, stream>>>(bsum, bbase, S, nbs, L);
  k_gsc3<<<nbs, 256, 0, stream>>>(bh, bbase, S, L);
  k_scatter<<<BLK, 256, 0, stream>>>(src, dstp, S, packed, E, EPB, NBk);
  k_build<<<NBk, 256, 0, stream>>>(packed, S, csr, off, dinv, n, NBk);

  k_proj1<<<(n + 15) / 16, 256, 0, stream>>>((const float4*)x, W1, dinv, h1p, n);
  k_agg64_proj2<<<gw4, 256, 0, stream>>>((const u32*)h1p, dinv, off, csr, b1, W2, h2p, n);
  k_agg32_tree<<<gw4, 256, 0, stream>>>((const u32*)h2p, dinv, off, csr, b2, gw, gb, lw, out, n);
}

// Round 13
// 402.944 us; speedup vs baseline: 1.1380x; 1.1380x over previous
//
#include <hip/hip_runtime.h>
#include <math.h>

#define IN_DIM 128
#define H1 64
#define H2 32
#define NC 8
#define SCAN_CH 1024   // elements per scan block (256 threads x 4)
#define NB_MAX 512     // max buckets (n <= 131072)
#define BLK 512        // edge partition blocks
#define CAP 12288      // LDS staging capacity per bucket (entries)

typedef unsigned int u32;

__device__ __forceinline__ float bf_lo(u32 u) { return __uint_as_float(u << 16); }
__device__ __forceinline__ float bf_hi(u32 u) { return __uint_as_float(u & 0xffff0000u); }
__device__ __forceinline__ unsigned short f2b(float f) {  // RNE float->bf16
  u32 u = __float_as_uint(f);
  u += 0x7fffu + ((u >> 16) & 1u);
  return (unsigned short)(u >> 16);
}

// ---------------- P1: per-block bucket histogram (LDS atomics only) ----------------
// bucket(d) = d >> 8 (256 nodes per bucket).

__global__ __launch_bounds__(256) void k_hist(const int* __restrict__ dst,
                                              int* __restrict__ bh,
                                              int E, int EPB, int NBk) {
  __shared__ int h[NB_MAX];
  int k = blockIdx.x, tid = threadIdx.x;
  for (int i = tid; i < NBk; i += 256) h[i] = 0;
  __syncthreads();
  int st = k * EPB, en = min(E, st + EPB);
  for (int i = st + tid; i < en; i += 256)
    atomicAdd(&h[((u32)dst[i]) >> 8], 1);
  __syncthreads();
  for (int b = tid; b < NBk; b += 256) bh[b * BLK + k] = h[b];
}

// ---- generic 3-phase exclusive scan of A[L] -> S[L], S[L] = total ----

__global__ __launch_bounds__(256) void k_gsc1(const int* __restrict__ A,
                                              int* __restrict__ bsum, int L) {
  int b = blockIdx.x, tid = threadIdx.x;
  int i0 = b * SCAN_CH + tid * 4;
  int s = 0;
  if (i0 + 3 < L) {
    int4 v = *(const int4*)(A + i0);
    s = v.x + v.y + v.z + v.w;
  } else {
    for (int i = i0; i < L; ++i) s += A[i];
  }
  __shared__ int red[256];
  red[tid] = s;
  __syncthreads();
  for (int d = 128; d > 0; d >>= 1) {
    if (tid < d) red[tid] += red[tid + d];
    __syncthreads();
  }
  if (tid == 0) bsum[b] = red[0];
}

__global__ __launch_bounds__(256) void k_gsc2(const int* __restrict__ bsum,
                                              int* __restrict__ bbase,
                                              int* __restrict__ S, int nbk, int L) {
  __shared__ int part[256];
  int tid = threadIdx.x;
  int chunk = (nbk + 255) / 256;
  int st = tid * chunk, en = min(st + chunk, nbk);
  int s = 0;
  for (int i = st; i < en; ++i) s += bsum[i];
  part[tid] = s;
  __syncthreads();
  for (int d = 1; d < 256; d <<= 1) {
    int t = (tid >= d) ? part[tid - d] : 0;
    __syncthreads();
    part[tid] += t;
    __syncthreads();
  }
  int base = (tid == 0) ? 0 : part[tid - 1];
  for (int i = st; i < en; ++i) { bbase[i] = base; base += bsum[i]; }
  if (tid == 255) S[L] = part[255];
}

__global__ __launch_bounds__(256) void k_gsc3(const int* __restrict__ A,
                                              const int* __restrict__ bbase,
                                              int* __restrict__ S, int L) {
  int b = blockIdx.x, tid = threadIdx.x;
  int i0 = b * SCAN_CH + tid * 4;
  int e0 = 0, e1 = 0, e2 = 0, e3 = 0;
  if (i0 + 3 < L) {
    int4 v = *(const int4*)(A + i0);
    e0 = v.x; e1 = v.y; e2 = v.z; e3 = v.w;
  } else {
    if (i0 + 0 < L) e0 = A[i0 + 0];
    if (i0 + 1 < L) e1 = A[i0 + 1];
    if (i0 + 2 < L) e2 = A[i0 + 2];
    if (i0 + 3 < L) e3 = A[i0 + 3];
  }
  __shared__ int part[256];
  part[tid] = e0 + e1 + e2 + e3;
  __syncthreads();
  for (int d = 1; d < 256; d <<= 1) {
    int t = (tid >= d) ? part[tid - d] : 0;
    __syncthreads();
    part[tid] += t;
    __syncthreads();
  }
  int base = bbase[b] + ((tid == 0) ? 0 : part[tid - 1]);
  int o0 = base, o1 = o0 + e0, o2 = o1 + e1, o3 = o2 + e2;
  if (i0 + 3 < L) {
    int4 o; o.x = o0; o.y = o1; o.z = o2; o.w = o3;
    *(int4*)(S + i0) = o;
  } else {
    if (i0 + 0 < L) S[i0 + 0] = o0;
    if (i0 + 1 < L) S[i0 + 1] = o1;
    if (i0 + 2 < L) S[i0 + 2] = o2;
    if (i0 + 3 < L) S[i0 + 3] = o3;
  }
}

// ---------------- P3: bucket scatter (LDS cursors, disjoint global ranges) ----------------
// packed entry: bits[0,17) = src, bits[17,25) = local node id within bucket.

__global__ __launch_bounds__(256) void k_scatter(const int* __restrict__ src,
                                                 const int* __restrict__ dst,
                                                 const int* __restrict__ S,
                                                 u32* __restrict__ packed,
                                                 int E, int EPB, int NBk) {
  __shared__ int cur[NB_MAX];
  int k = blockIdx.x, tid = threadIdx.x;
  for (int b = tid; b < NBk; b += 256) cur[b] = S[b * BLK + k];
  __syncthreads();
  int st = k * EPB, en = min(E, st + EPB);
  for (int i = st + tid; i < en; i += 256) {
    int d = dst[i];
    int b = ((u32)d) >> 8;
    int pos = atomicAdd(&cur[b], 1);
    packed[pos] = (((u32)d & 255u) << 17) | (u32)src[i];
  }
}

// ---------------- P4: per-bucket CSR build + off + dinv ----------------
// Sort order staged in LDS (sbuf), csr written COALESCED (R5/R13 lesson:
// scattered 4B global stores cost ~16x write-line amplification).

__global__ __launch_bounds__(256) void k_build(const u32* __restrict__ packed,
                                               const int* __restrict__ S,
                                               int* __restrict__ csr,
                                               int* __restrict__ off,
                                               float* __restrict__ dinv,
                                               int n, int NBk) {
  __shared__ int cnt[256];
  __shared__ int tmp[256];
  __shared__ int cur[256];
  __shared__ int sbuf[CAP];  // 48 KB staging
  int b = blockIdx.x, tid = threadIdx.x;
  int r0 = S[b * BLK];
  int r1 = S[(b + 1) * BLK];  // for last bucket: S[L] = E
  int m = r1 - r0;
  cnt[tid] = 0;
  __syncthreads();
  for (int i = r0 + tid; i < r1; i += 256)
    atomicAdd(&cnt[packed[i] >> 17], 1);
  __syncthreads();
  int v = cnt[tid];
  tmp[tid] = v;
  __syncthreads();
  for (int d = 1; d < 256; d <<= 1) {
    int t = (tid >= d) ? tmp[tid - d] : 0;
    __syncthreads();
    tmp[tid] += t;
    __syncthreads();
  }
  int rel = tmp[tid] - v;  // exclusive prefix within bucket
  int node = b * 256 + tid;
  if (node < n) {
    off[node] = r0 + rel;
    dinv[node] = rsqrtf((float)(v + 1));  // +1 self-loop
  }
  if (b == NBk - 1 && tid == 0) off[n] = r1;
  cur[tid] = rel;
  __syncthreads();
  if (m <= CAP) {
    // scatter into LDS (cheap), then stream out coalesced
    for (int i = r0 + tid; i < r1; i += 256) {
      u32 u = packed[i];
      int pos = atomicAdd(&cur[u >> 17], 1);
      sbuf[pos] = (int)(u & 0x1FFFFu);
    }
    __syncthreads();
    for (int j = tid; j < m; j += 256)
      csr[r0 + j] = sbuf[j];
  } else {
    // fallback: scattered global writes (statistically unreachable)
    for (int i = r0 + tid; i < r1; i += 256) {
      u32 u = packed[i];
      int pos = atomicAdd(&cur[u >> 17], 1);
      csr[r0 + pos] = (int)(u & 0x1FFFFu);
    }
  }
}

// ---------------- projection 1: h1p = bf16(dinv * (x @ W1^T))  [n,128]->[n,64] ----------------

__global__ void k_proj1(const float4* __restrict__ x4, const float* __restrict__ W1,
                        const float* __restrict__ dinv,
                        unsigned short* __restrict__ h1p, int n) {
  __shared__ float xs[16][IN_DIM];
  __shared__ float wt[IN_DIM][H1 + 1];
  int tid = threadIdx.x;
  int row0 = blockIdx.x * 16;

  for (int i = tid; i < (H1 * IN_DIM / 4); i += 256) {
    float4 w = ((const float4*)W1)[i];
    int o = (i * 4) / IN_DIM;
    int k = (i * 4) % IN_DIM;
    wt[k + 0][o] = w.x; wt[k + 1][o] = w.y; wt[k + 2][o] = w.z; wt[k + 3][o] = w.w;
  }
  for (int i = tid; i < 16 * IN_DIM / 4; i += 256) {
    int r = (i * 4) / IN_DIM, k = (i * 4) % IN_DIM;
    int row = row0 + r;
    if (row < n)
      *((float4*)&xs[r][k]) = x4[(size_t)row * (IN_DIM / 4) + k / 4];
  }
  __syncthreads();

  int o = tid & 63, rq = tid >> 6;
  float a0 = 0.f, a1 = 0.f, a2 = 0.f, a3 = 0.f;
  for (int k = 0; k < IN_DIM; ++k) {
    float w = wt[k][o];
    a0 += xs[rq * 4 + 0][k] * w;
    a1 += xs[rq * 4 + 1][k] * w;
    a2 += xs[rq * 4 + 2][k] * w;
    a3 += xs[rq * 4 + 3][k] * w;
  }
  int r = row0 + rq * 4;
  if (r + 0 < n) h1p[(size_t)(r + 0) * H1 + o] = f2b(a0 * dinv[r + 0]);
  if (r + 1 < n) h1p[(size_t)(r + 1) * H1 + o] = f2b(a1 * dinv[r + 1]);
  if (r + 2 < n) h1p[(size_t)(r + 2) * H1 + o] = f2b(a2 * dinv[r + 2]);
  if (r + 3 < n) h1p[(size_t)(r + 3) * H1 + o] = f2b(a3 * dinv[r + 3]);
}

// ---------------- fused: layer-1 gather-agg + bias + relu + proj2 ----------------
// Half-wave per edge slot; unroll x4 => 8 edges in flight per wave (R9 config,
// best measured; x8 was neutral (R11), nt-hints regressed (R12)).

__global__ __launch_bounds__(256) void k_agg64_proj2(
    const u32* __restrict__ hp,    // [n][32] packed bf16x2
    const float* __restrict__ dinv,
    const int* __restrict__ off, const int* __restrict__ csr,
    const float* __restrict__ b1, const float* __restrict__ W2,
    unsigned short* __restrict__ h2p, int n) {
  __shared__ float wt[H1][H2 + 1];   // W2 transposed: wt[k][o]
  __shared__ float rows[4][H1];      // relu(out1) row per wave
  int tid = threadIdx.x;

  for (int i = tid; i < H2 * H1 / 4; i += 256) {
    float4 w = ((const float4*)W2)[i];
    int o = (i * 4) / H1, k = (i * 4) % H1;
    wt[k + 0][o] = w.x; wt[k + 1][o] = w.y; wt[k + 2][o] = w.z; wt[k + 3][o] = w.w;
  }

  int lane = tid & 63;
  int wv = __builtin_amdgcn_readfirstlane(tid >> 6);
  int wid0 = blockIdx.x * 4 + wv;
  int wid = wid0 < n ? wid0 : n - 1;   // clamp so all waves reach barriers
  int half = lane >> 5, f2 = lane & 31;

  float ax = 0.f, ay = 0.f;
  if (half == 0) {  // self term (table already has dinv[self] folded in)
    u32 u = hp[(size_t)wid * (H1 / 2) + f2];
    ax = bf_lo(u); ay = bf_hi(u);
  }
  int r0 = off[wid], r1 = off[wid + 1];
  int i = r0 + half;
  for (; i + 6 < r1; i += 8) {
    int s0 = csr[i + 0], s1 = csr[i + 2], s2 = csr[i + 4], s3 = csr[i + 6];
    u32 u0 = hp[(size_t)s0 * (H1 / 2) + f2];
    u32 u1 = hp[(size_t)s1 * (H1 / 2) + f2];
    u32 u2 = hp[(size_t)s2 * (H1 / 2) + f2];
    u32 u3 = hp[(size_t)s3 * (H1 / 2) + f2];
    ax += bf_lo(u0); ay += bf_hi(u0);
    ax += bf_lo(u1); ay += bf_hi(u1);
    ax += bf_lo(u2); ay += bf_hi(u2);
    ax += bf_lo(u3); ay += bf_hi(u3);
  }
  for (; i < r1; i += 2) {
    u32 u = hp[(size_t)csr[i] * (H1 / 2) + f2];
    ax += bf_lo(u);
    ay += bf_hi(u);
  }
  ax += __shfl_down(ax, 32, 64);
  ay += __shfl_down(ay, 32, 64);
  float d = dinv[wid];
  if (half == 0) {
    float2 rv;
    rv.x = fmaxf(ax * d + b1[2 * f2 + 0], 0.f);
    rv.y = fmaxf(ay * d + b1[2 * f2 + 1], 0.f);
    *(float2*)&rows[wv][2 * f2] = rv;
  }
  __syncthreads();

  // proj2: half-wave split over k, 32 outputs per node
  int o = lane & 31;
  float a = 0.f;
#pragma unroll
  for (int k = 0; k < 32; ++k) {
    int kk = half * 32 + k;
    a += rows[wv][kk] * wt[kk][o];
  }
  a += __shfl_down(a, 32, 64);
  if (half == 0 && wid0 < n) h2p[(size_t)wid0 * H2 + o] = f2b(a * d);
}

// ---------------- fused: layer-2 gather-agg + b2 + gates + leaf ----------------
// Quarter-wave per edge slot; unroll x4 => 16 edges in flight per wave.

__global__ __launch_bounds__(256) void k_agg32_tree(
    const u32* __restrict__ hp,    // [n][16] packed bf16x2
    const float* __restrict__ dinv,
    const int* __restrict__ off, const int* __restrict__ csr,
    const float* __restrict__ b2, const float* __restrict__ gate_w,
    const float* __restrict__ gate_b, const float* __restrict__ leaf_w,
    float* __restrict__ out, int n) {
  __shared__ float gwt[H2][H2 + 1];  // gate_w transposed: gwt[k][j]
  __shared__ float lws[H2][NC + 1];
  __shared__ float rowh[4][H2];
  __shared__ float rowg[4][H2];
  int tid = threadIdx.x;

  {
    float4 w = ((const float4*)gate_w)[tid];  // H2*H2/4 == 256
    int j = (tid * 4) / H2, k = (tid * 4) % H2;
    gwt[k + 0][j] = w.x; gwt[k + 1][j] = w.y; gwt[k + 2][j] = w.z; gwt[k + 3][j] = w.w;
  }
  lws[tid >> 3][tid & 7] = leaf_w[tid];  // H2*NC == 256

  int lane = tid & 63;
  int wv = __builtin_amdgcn_readfirstlane(tid >> 6);
  int wid0 = blockIdx.x * 4 + wv;
  int wid = wid0 < n ? wid0 : n - 1;
  int q = lane >> 4, f2 = lane & 15;

  float ax = 0.f, ay = 0.f;
  if (q == 0) {  // self term
    u32 u = hp[(size_t)wid * (H2 / 2) + f2];
    ax = bf_lo(u); ay = bf_hi(u);
  }
  int r0 = off[wid], r1 = off[wid + 1];
  int i = r0 + q;
  for (; i + 12 < r1; i += 16) {
    int s0 = csr[i + 0], s1 = csr[i + 4], s2 = csr[i + 8], s3 = csr[i + 12];
    u32 u0 = hp[(size_t)s0 * (H2 / 2) + f2];
    u32 u1 = hp[(size_t)s1 * (H2 / 2) + f2];
    u32 u2 = hp[(size_t)s2 * (H2 / 2) + f2];
    u32 u3 = hp[(size_t)s3 * (H2 / 2) + f2];
    ax += bf_lo(u0); ay += bf_hi(u0);
    ax += bf_lo(u1); ay += bf_hi(u1);
    ax += bf_lo(u2); ay += bf_hi(u2);
    ax += bf_lo(u3); ay += bf_hi(u3);
  }
  for (; i < r1; i += 4) {
    u32 u = hp[(size_t)csr[i] * (H2 / 2) + f2];
    ax += bf_lo(u);
    ay += bf_hi(u);
  }
  ax += __shfl_down(ax, 32, 64); ay += __shfl_down(ay, 32, 64);
  ax += __shfl_down(ax, 16, 64); ay += __shfl_down(ay, 16, 64);
  float d = dinv[wid];
  if (lane < 16) {
    float2 rv;
    rv.x = ax * d + b2[2 * f2 + 0];
    rv.y = ay * d + b2[2 * f2 + 1];
    *(float2*)&rowh[wv][2 * f2] = rv;
  }
  __syncthreads();

  // gates: j = f, half-wave split over k (16 each)
  int half = lane >> 5, f = lane & 31;
  float g = 0.f;
#pragma unroll
  for (int k = 0; k < 16; ++k) {
    int kk = half * 16 + k;
    g += rowh[wv][kk] * gwt[kk][f];
  }
  g += __shfl_down(g, 32, 64);
  if (half == 0) rowg[wv][f] = 1.0f / (1.0f + __expf(-(g + gate_b[f])));
  __syncthreads();

  // leaf: 8 groups of 8 lanes
  int c = lane & 7, gi = lane >> 3;
  float a = 0.f;
#pragma unroll
  for (int j4 = 0; j4 < 4; ++j4) {
    int jj = gi * 4 + j4;
    a += rowg[wv][jj] * lws[jj][c];
  }
  a += __shfl_down(a, 32, 64);
  a += __shfl_down(a, 16, 64);
  a += __shfl_down(a, 8, 64);
  if (lane < 8 && wid0 < n) out[(size_t)wid0 * NC + lane] = a;
}

// ---------------- host ----------------

extern "C" void kernel_launch(void* const* d_in, const int* in_sizes, int n_in,
                              void* d_out, int out_size, void* d_ws, size_t ws_size,
                              hipStream_t stream) {
  const float* x  = (const float*)d_in[0];
  const int*   ei = (const int*)d_in[1];
  const float* W1 = (const float*)d_in[2];
  const float* b1 = (const float*)d_in[3];
  const float* W2 = (const float*)d_in[4];
  const float* b2 = (const float*)d_in[5];
  const float* gw = (const float*)d_in[6];
  const float* gb = (const float*)d_in[7];
  const float* lw = (const float*)d_in[8];
  float* out = (float*)d_out;

  int n = in_sizes[0] / IN_DIM;
  int E = in_sizes[1] / 2;
  const int* src  = ei;
  const int* dstp = ei + E;

  int NBk = (n + 255) >> 8;                    // buckets of 256 nodes
  int EPB = (E + BLK - 1) / BLK;               // edges per partition block
  int L   = NBk * BLK;                         // blockhist entries
  int nbs = (L + SCAN_CH - 1) / SCAN_CH;       // scan blocks

  // workspace layout (16B-aligned chunks)
  size_t n4  = ((size_t)n + 3) & ~(size_t)3;
  size_t np4 = ((size_t)n + 1 + 3) & ~(size_t)3;
  size_t E4  = ((size_t)E + 3) & ~(size_t)3;
  size_t L4  = ((size_t)L + 1 + 3) & ~(size_t)3;
  size_t nbs4 = ((size_t)nbs + 3) & ~(size_t)3;
  char* w = (char*)d_ws;
  int* csr    = (int*)w;   w += E4 * 4;
  u32* packed = (u32*)w;   w += E4 * 4;
  int* bh     = (int*)w;   w += L4 * 4;
  int* S      = (int*)w;   w += L4 * 4;
  int* bsum   = (int*)w;   w += nbs4 * 4;
  int* bbase  = (int*)w;   w += nbs4 * 4;
  float* dinv = (float*)w; w += n4 * 4;
  int* off    = (int*)w;   w += np4 * 4;
  unsigned short* h1p = (unsigned short*)w;  w += n4 * (size_t)H1 * 2;  // bf16 [n][64]
  unsigned short* h2p = (unsigned short*)w;                             // bf16 [n][32]

  int gw4 = (n + 3) / 4;  // 4 nodes per 256-thread block

  k_hist<<<BLK, 256, 0, stream>>>(dstp, bh, E, EPB, NBk);
  k_gsc1<<<nbs, 256, 0, stream>>>(bh, bsum, L);
  k_gsc2<<<1, 256, 0, stream>>>(bsum, bbase, S, nbs, L);
  k_gsc3<<<nbs, 256, 0, stream>>>(bh, bbase, S, L);
  k_scatter<<<BLK, 256, 0, stream>>>(src, dstp, S, packed, E, EPB, NBk);
  k_build<<<NBk, 256, 0, stream>>>(packed, S, csr, off, dinv, n, NBk);

  k_proj1<<<(n + 15) / 16, 256, 0, stream>>>((const float4*)x, W1, dinv, h1p, n);
  k_agg64_proj2<<<gw4, 256, 0, stream>>>((const u32*)h1p, dinv, off, csr, b1, W2, h2p, n);
  k_agg32_tree<<<gw4, 256, 0, stream>>>((const u32*)h2p, dinv, off, csr, b2, gw, gb, lw, out, n);
}